// Round 11
// baseline (675.876 us; speedup 1.0000x reference)
//
#include <hip/hip_runtime.h>

#define N_POINTS 100000
#define N_PAIRS  50000
#define K_OFFSETS 27
#define C 128
#define WPAD 136   // 128 + 8 bf16 pad; LDS row stride 272B
#define CAP 48     // per-point list capacity; Poisson(13.5), P(>=48) ~ 3e-12

// Point-quarter CSR (round-9 verified): per (h,k) bucket k-pure & contiguous ->
// conv writes msg linearly; gather reads each point once per layer.
#define NQ 4
#define QPTS 25000
#define MSGCAP 344064      // slots per quarter; mean 337.9K incl pads, +11 sigma
#define GX 110             // conv blocks per k: 110*128 = 14080 >= cnt_hk (+14 sigma)

// XCD-partitioned build (round-2 proven)
#define CSR_GROUPS 8
#define CSR_BPG 128

typedef __attribute__((ext_vector_type(8))) short short8;
typedef __attribute__((ext_vector_type(4))) float floatx4;
typedef __attribute__((ext_vector_type(4))) int intx4;   // clang vector: valid for nontemporal builtins

__device__ inline unsigned short f2bf(float f) {
  unsigned int u = __float_as_uint(f);
  return (unsigned short)((u + 0x7FFFu + ((u >> 16) & 1u)) >> 16);  // RNE
}
__device__ inline float bf2f(unsigned int lo16) {
  return __uint_as_float(lo16 << 16);
}

// WT[k][d*C + c] = bf16(W[k][c][d])  -- natural order for BOTH layers
__global__ __launch_bounds__(256) void prep_w_kernel(
    const float* __restrict__ W0, const float* __restrict__ W1,
    unsigned short* __restrict__ WT0, unsigned short* __restrict__ WT1) {
  int i = blockIdx.x * 256 + threadIdx.x;
  const int per = K_OFFSETS * C * C;
  if (i >= 2 * per) return;
  const float* W = (i < per) ? W0 : W1;
  unsigned short* WT = (i < per) ? WT0 : WT1;
  int r = (i < per) ? i : i - per;
  int k = r / (C * C);
  int q = r % (C * C);
  int d = q / C;
  int c = q % C;
  WT[k * C * C + d * C + c] = f2bf(W[k * C * C + c * C + d]);
}

// xb = bf16(features); out = broadcast(b0) only on the fallback path
__global__ __launch_bounds__(256) void prep_x_kernel(
    const float* __restrict__ features, const float* __restrict__ b0,
    unsigned short* __restrict__ xb, float* __restrict__ out, int write_out) {
  int i = (blockIdx.x * 256 + threadIdx.x) * 4;
  if (i >= N_POINTS * C) return;
  float4 f = *(const float4*)&features[i];
  ushort4 u;
  u.x = f2bf(f.x); u.y = f2bf(f.y); u.z = f2bf(f.z); u.w = f2bf(f.w);
  *(ushort4*)&xb[i] = u;
  if (write_out) {
    float4 b = *(const float4*)&b0[i & 127];
    *(float4*)&out[i] = b;
  }
}

__global__ __launch_bounds__(256) void zero_meta_kernel(
    int* __restrict__ counts, int* __restrict__ counts_hk) {
  int i = blockIdx.x * 256 + threadIdx.x;
  if (i < N_POINTS) counts[i] = 0;
  if (i < NQ * K_OFFSETS) counts_hk[i] = 0;
}

// Pass 1: per-(quarter,k) totals. LDS histogram; nt loads keep the stream out of L2.
__global__ __launch_bounds__(256) void count_hk_kernel(
    const int* __restrict__ out_map, int* __restrict__ counts_hk) {
  __shared__ int hist[NQ * K_OFFSETS];
  if (threadIdx.x < NQ * K_OFFSETS) hist[threadIdx.x] = 0;
  __syncthreads();
  const int total4 = K_OFFSETS * N_PAIRS / 4;
  for (int i4 = blockIdx.x * 256 + (int)threadIdx.x; i4 < total4; i4 += 256 * 256) {
    intx4 o4 = __builtin_nontemporal_load((const intx4*)&out_map[i4 * 4]);
    int o[4] = {o4.x, o4.y, o4.z, o4.w};
    int k = (i4 * 4) / N_PAIRS;
#pragma unroll
    for (int j = 0; j < 4; ++j) atomicAdd(&hist[(o[j] / QPTS) * K_OFFSETS + k], 1);
  }
  __syncthreads();
  if (threadIdx.x < NQ * K_OFFSETS)
    atomicAdd(&counts_hk[threadIdx.x], hist[threadIdx.x]);
}

// Pass 2: exclusive scan of 32-padded bucket sizes, per quarter.
__global__ void scan_kernel(const int* __restrict__ counts_hk,
                            int* __restrict__ base_hk, int* __restrict__ cursor_hk) {
  if (threadIdx.x < NQ) {
    int h = threadIdx.x;
    int run = 0;
    for (int k = 0; k < K_OFFSETS; ++k) {
      base_hk[h * K_OFFSETS + k] = run;
      cursor_hk[h * K_OFFSETS + k] = run;
      run += (counts_hk[h * K_OFFSETS + k] + 31) & ~31;
    }
  }
}

// Pass 3: slot assignment + per-point lists. Two-level alloc (LDS hist -> one
// cursor atomicAdd per (block,k)). NT loads on both map streams so the
// accumulating idxbuf/counts/pairlist lines stay L2-resident (round-9 showed
// 71 MB writebacks vs 11 logical from stream-induced eviction).
__global__ __launch_bounds__(256) void build2_kernel(
    const int* __restrict__ out_map, const int* __restrict__ in_map,
    int* __restrict__ counts, int* __restrict__ idxbuf,
    int* __restrict__ cursor_hk, int* __restrict__ pairlist) {
  __shared__ int histA[K_OFFSETS];
  __shared__ int kbase[K_OFFSETS];
  const int grp = blockIdx.x & (CSR_GROUPS - 1);
  const int blk = blockIdx.x >> 3;
  const int h = grp >> 1;
  const int lo = grp * (N_POINTS / CSR_GROUPS);
  const int hi = lo + (N_POINTS / CSR_GROUPS);
  if (threadIdx.x < K_OFFSETS) histA[threadIdx.x] = 0;
  __syncthreads();
  const int total4 = K_OFFSETS * N_PAIRS / 4;
  for (int i4 = blk * 256 + (int)threadIdx.x; i4 < total4; i4 += CSR_BPG * 256) {
    intx4 o4 = __builtin_nontemporal_load((const intx4*)&out_map[i4 * 4]);
    int o[4] = {o4.x, o4.y, o4.z, o4.w};
    int k = (i4 * 4) / N_PAIRS;
#pragma unroll
    for (int j = 0; j < 4; ++j)
      if (o[j] >= lo && o[j] < hi) atomicAdd(&histA[k], 1);
  }
  __syncthreads();
  if (threadIdx.x < K_OFFSETS) {
    kbase[threadIdx.x] =
        atomicAdd(&cursor_hk[h * K_OFFSETS + threadIdx.x], histA[threadIdx.x]);
    histA[threadIdx.x] = 0;
  }
  __syncthreads();
  for (int i4 = blk * 256 + (int)threadIdx.x; i4 < total4; i4 += CSR_BPG * 256) {
    intx4 o4 = __builtin_nontemporal_load((const intx4*)&out_map[i4 * 4]);
    intx4 n4 = __builtin_nontemporal_load((const intx4*)&in_map[i4 * 4]);
    int o[4] = {o4.x, o4.y, o4.z, o4.w};
    int n[4] = {n4.x, n4.y, n4.z, n4.w};
    int k = (i4 * 4) / N_PAIRS;
#pragma unroll
    for (int j = 0; j < 4; ++j) {
      if (o[j] >= lo && o[j] < hi) {
        int pk = atomicAdd(&histA[k], 1);
        int slot = kbase[k] + pk;
        pairlist[h * MSGCAP + slot] = n[j];
        int pos = atomicAdd(&counts[o[j]], 1);
        if (pos < CAP) idxbuf[o[j] * CAP + pos] = slot;
      }
    }
  }
}

// Conv (quarters h0..h0+gridDim.z-1): wave = 32 contiguous slots = 2 A-tiles.
// pairlist coalesced, msg writes LINEAR, W from LDS (baseline MFMA core).
__global__ __launch_bounds__(256, 4) void conv2_kernel(
    const unsigned short* __restrict__ xin, const unsigned short* __restrict__ wbt,
    const int* __restrict__ counts_hk, const int* __restrict__ base_hk,
    const int* __restrict__ pairlist, unsigned short* __restrict__ msg2, int h0) {
  __shared__ unsigned short Wlds[C * WPAD];
  const int h = h0 + blockIdx.z;
  const int k = blockIdx.y;
  const int cnt = counts_hk[h * K_OFFSETS + k];
  const int cpad = (cnt + 31) & ~31;
  const int off0 = blockIdx.x * 128;
  if (off0 >= cpad) return;            // block-uniform, before any barrier
  const int kb = base_hk[h * K_OFFSETS + k];
  const int tid = threadIdx.x;

  const unsigned short* wk = wbt + k * C * C;
#pragma unroll
  for (int it = 0; it < 8; ++it) {
    int t = tid + it * 256;
    int row = t >> 4;
    int col = (t & 15) << 3;
    *(uint4*)&Wlds[row * WPAD + col] = *(const uint4*)&wk[row * C + col];
  }
  __syncthreads();

  const int wave = tid >> 6;
  const int lane = tid & 63;
  const int l15 = lane & 15;
  const int kg = lane >> 4;
  const int ws0 = off0 + wave * 32;
  if (ws0 >= cpad) return;             // wave-uniform (32-aligned windows)

  const int s0 = kb + ws0;
  const int plbase = h * MSGCAP;
  const int n0 = pairlist[plbase + s0 + l15] & 0x1FFFF;
  const int n1 = pairlist[plbase + s0 + 16 + l15] & 0x1FFFF;
  const unsigned short* arow0 = xin + (size_t)n0 * C + kg * 8;
  const unsigned short* arow1 = xin + (size_t)n1 * C + kg * 8;

  floatx4 acc0[8], acc1[8];
#pragma unroll
  for (int nt = 0; nt < 8; ++nt) {
    acc0[nt] = (floatx4){0.f, 0.f, 0.f, 0.f};
    acc1[nt] = (floatx4){0.f, 0.f, 0.f, 0.f};
  }
#pragma unroll
  for (int kk = 0; kk < 4; ++kk) {
    short8 a0 = *(const short8*)(arow0 + kk * 32);
    short8 a1 = *(const short8*)(arow1 + kk * 32);
    const unsigned short* bbase = &Wlds[l15 * WPAD + kk * 32 + kg * 8];
#pragma unroll
    for (int nt = 0; nt < 8; ++nt) {
      short8 b = *(const short8*)(bbase + nt * 16 * WPAD);
      acc0[nt] = __builtin_amdgcn_mfma_f32_16x16x32_bf16(a0, b, acc0[nt], 0, 0, 0);
      acc1[nt] = __builtin_amdgcn_mfma_f32_16x16x32_bf16(a1, b, acc1[nt], 0, 0, 0);
    }
  }
  unsigned short* mz = msg2 + (size_t)blockIdx.z * MSGCAP * C;
#pragma unroll
  for (int i = 0; i < 4; ++i) {
    {
      unsigned short* row = mz + (size_t)(s0 + kg * 4 + i) * C;
      uint4 v;
      v.x = (unsigned int)f2bf(acc0[0][i]) | ((unsigned int)f2bf(acc0[1][i]) << 16);
      v.y = (unsigned int)f2bf(acc0[2][i]) | ((unsigned int)f2bf(acc0[3][i]) << 16);
      v.z = (unsigned int)f2bf(acc0[4][i]) | ((unsigned int)f2bf(acc0[5][i]) << 16);
      v.w = (unsigned int)f2bf(acc0[6][i]) | ((unsigned int)f2bf(acc0[7][i]) << 16);
      *(uint4*)(row + l15 * 8) = v;
    }
    {
      unsigned short* row = mz + (size_t)(s0 + 16 + kg * 4 + i) * C;
      uint4 v;
      v.x = (unsigned int)f2bf(acc1[0][i]) | ((unsigned int)f2bf(acc1[1][i]) << 16);
      v.y = (unsigned int)f2bf(acc1[2][i]) | ((unsigned int)f2bf(acc1[3][i]) << 16);
      v.z = (unsigned int)f2bf(acc1[4][i]) | ((unsigned int)f2bf(acc1[5][i]) << 16);
      v.w = (unsigned int)f2bf(acc1[6][i]) | ((unsigned int)f2bf(acc1[7][i]) << 16);
      *(uint4*)(row + l15 * 8) = v;
    }
  }
}

// Gather (batched quarters): one wave per point, one pass over all 27 k.
__global__ __launch_bounds__(256) void gather2_kernel(
    const unsigned short* __restrict__ msg2, const int* __restrict__ counts,
    const int* __restrict__ idxbuf, const float* __restrict__ bias,
    const float* __restrict__ features, float* __restrict__ out,
    unsigned short* __restrict__ x1b, int h0, int layer) {
  __shared__ int elds[4][64];
  const int wave = threadIdx.x >> 6;
  const int lane = threadIdx.x & 63;
  const int z = blockIdx.x / (QPTS / 4);
  const int bx = blockIdx.x - z * (QPTS / 4);
  const int oi = (h0 + z) * QPTS + bx * 4 + wave;

  const int c0 = ((2 * lane) & 7) * 16 + (lane >> 2);
  const int c1 = c0 + 16;
  const size_t base = (size_t)oi * C;

  float a0, a1;
  if (layer == 0) { a0 = bias[c0]; a1 = bias[c1]; }
  else            { a0 = bias[c0] + features[base + c0];
                    a1 = bias[c1] + features[base + c1]; }

  int cnt = counts[oi]; if (cnt > CAP) cnt = CAP;
  if (lane < cnt) elds[wave][lane] = idxbuf[oi * CAP + lane];
  __syncthreads();

  const unsigned short* mb = msg2 + (size_t)z * MSGCAP * C + 2 * lane;
  int t = 0;
  for (; t + 4 <= cnt; t += 4) {
    int f0 = elds[wave][t];
    int f1 = elds[wave][t + 1];
    int f2 = elds[wave][t + 2];
    int f3 = elds[wave][t + 3];
    unsigned int v0 = *(const unsigned int*)(mb + (size_t)f0 * C);
    unsigned int v1 = *(const unsigned int*)(mb + (size_t)f1 * C);
    unsigned int v2 = *(const unsigned int*)(mb + (size_t)f2 * C);
    unsigned int v3 = *(const unsigned int*)(mb + (size_t)f3 * C);
    a0 += bf2f(v0 & 0xffffu) + bf2f(v1 & 0xffffu) + bf2f(v2 & 0xffffu) + bf2f(v3 & 0xffffu);
    a1 += bf2f(v0 >> 16) + bf2f(v1 >> 16) + bf2f(v2 >> 16) + bf2f(v3 >> 16);
  }
  for (; t < cnt; ++t) {
    int f0 = elds[wave][t];
    unsigned int v = *(const unsigned int*)(mb + (size_t)f0 * C);
    a0 += bf2f(v & 0xffffu);
    a1 += bf2f(v >> 16);
  }

  if (layer == 0) {
    x1b[base + c0] = f2bf(fmaxf(a0, 0.f));
    x1b[base + c1] = f2bf(fmaxf(a1, 0.f));
  } else {
    out[base + c0] = a0;
    out[base + c1] = a1;
  }
}

// ---------------- fallback (atomic path, small ws, natural WT) ----------------
__global__ __launch_bounds__(256) void mid_kernel(
    const float* __restrict__ features, const float* __restrict__ b1,
    float* __restrict__ out, unsigned short* __restrict__ x1b) {
  int i = (blockIdx.x * 256 + threadIdx.x) * 4;
  if (i >= N_POINTS * C) return;
  float4 y = *(const float4*)&out[i];
  ushort4 u;
  u.x = f2bf(fmaxf(y.x, 0.f));
  u.y = f2bf(fmaxf(y.y, 0.f));
  u.z = f2bf(fmaxf(y.z, 0.f));
  u.w = f2bf(fmaxf(y.w, 0.f));
  *(ushort4*)&x1b[i] = u;
  float4 f = *(const float4*)&features[i];
  float4 b = *(const float4*)&b1[i & 127];
  float4 o;
  o.x = f.x + b.x; o.y = f.y + b.y; o.z = f.z + b.z; o.w = f.w + b.w;
  *(float4*)&out[i] = o;
}

__global__ __launch_bounds__(256, 4) void conv_atomic_kernel(
    const unsigned short* __restrict__ xb, const unsigned short* __restrict__ wbt,
    const int* __restrict__ in_map, const int* __restrict__ out_map,
    float* __restrict__ out) {
  __shared__ unsigned short Wlds[C * WPAD];
  const int k = blockIdx.y;
  const int pairBase = blockIdx.x * 64;
  const int tid = threadIdx.x;
  const unsigned short* wk = wbt + k * C * C;
#pragma unroll
  for (int it = 0; it < 8; ++it) {
    int t = tid + it * 256;
    int row = t >> 4;
    int col = (t & 15) << 3;
    *(uint4*)&Wlds[row * WPAD + col] = *(const uint4*)&wk[row * C + col];
  }
  __syncthreads();
  const int wave = tid >> 6;
  const int lane = tid & 63;
  const int l15 = lane & 15;
  const int kg = lane >> 4;
  const int pair0 = pairBase + wave * 16;
  const int prA = pair0 + l15;
  const int inIdx = (prA < N_PAIRS) ? in_map[k * N_PAIRS + prA] : 0;
  const unsigned short* arow = xb + (size_t)inIdx * C + kg * 8;
  floatx4 acc[8];
#pragma unroll
  for (int nt = 0; nt < 8; ++nt) acc[nt] = (floatx4){0.f, 0.f, 0.f, 0.f};
#pragma unroll
  for (int kk = 0; kk < 4; ++kk) {
    short8 a = *(const short8*)(arow + kk * 32);
    const unsigned short* bbase = &Wlds[l15 * WPAD + kk * 32 + kg * 8];
#pragma unroll
    for (int nt = 0; nt < 8; ++nt) {
      short8 b = *(const short8*)(bbase + nt * 16 * WPAD);
      acc[nt] = __builtin_amdgcn_mfma_f32_16x16x32_bf16(a, b, acc[nt], 0, 0, 0);
    }
  }
#pragma unroll
  for (int i = 0; i < 4; ++i) {
    int pr = pair0 + kg * 4 + i;
    if (pr < N_PAIRS) {
      int oi = out_map[k * N_PAIRS + pr];
      float* orow = out + (size_t)oi * C + l15;
#pragma unroll
      for (int nt = 0; nt < 8; ++nt) atomicAdd(orow + nt * 16, acc[nt][i]);
    }
  }
}

extern "C" void kernel_launch(void* const* d_in, const int* in_sizes, int n_in,
                              void* d_out, int out_size, void* d_ws, size_t ws_size,
                              hipStream_t stream) {
  const float* features = (const float*)d_in[0];
  const int* in_map     = (const int*)d_in[1];
  const int* out_map    = (const int*)d_in[2];
  const float* W0       = (const float*)d_in[3];
  const float* b0       = (const float*)d_in[4];
  const float* W1       = (const float*)d_in[5];
  const float* b1       = (const float*)d_in[6];
  float* out = (float*)d_out;

  char* ws = (char*)d_ws;
  unsigned short* xb  = (unsigned short*)(ws);                  // 25,600,000
  unsigned short* x1b = (unsigned short*)(ws + 25600000);       // 25,600,000
  unsigned short* WT0 = (unsigned short*)(ws + 51200000);       //    884,736
  unsigned short* WT1 = (unsigned short*)(ws + 52084736);       //    884,736
  int* counts         = (int*)(ws + 52969472);                  //    400,384
  int* counts_hk      = (int*)(ws + 53369856);                  //        512
  int* base_hk        = (int*)(ws + 53370368);                  //        512
  int* cursor_hk      = (int*)(ws + 53370880);                  //        512
  int* pairlist       = (int*)(ws + 53371392);                  //  5,505,024 (4 x MSGCAP x 4)
  int* idxbuf         = (int*)(ws + 58876416);                  // 19,200,000 (100000*CAP*4)
  unsigned short* msg2 = (unsigned short*)(ws + 78076416);      // B x 88,080,384 (MSGCAP*256)
  // 1-batch end = 166,156,800 ; 2-batch end = 254,237,184

  const int use2  = (ws_size >= 166156800ULL) ? 1 : 0;
  const int BATCH = (ws_size >= 254237184ULL) ? 2 : 1;

  prep_w_kernel<<<(2 * K_OFFSETS * C * C + 255) / 256, 256, 0, stream>>>(W0, W1, WT0, WT1);
  prep_x_kernel<<<(N_POINTS * C / 4 + 255) / 256, 256, 0, stream>>>(
      features, b0, xb, out, use2 ? 0 : 1);

  if (use2) {
    zero_meta_kernel<<<(N_POINTS + 255) / 256, 256, 0, stream>>>(counts, counts_hk);
    count_hk_kernel<<<256, 256, 0, stream>>>(out_map, counts_hk);
    scan_kernel<<<1, 64, 0, stream>>>(counts_hk, base_hk, cursor_hk);
    build2_kernel<<<CSR_GROUPS * CSR_BPG, 256, 0, stream>>>(
        out_map, in_map, counts, idxbuf, cursor_hk, pairlist);

    for (int layer = 0; layer < 2; ++layer) {
      const unsigned short* xin = layer ? x1b : xb;
      const unsigned short* wt  = layer ? WT1 : WT0;
      const float* bias         = layer ? b1  : b0;
      for (int h0 = 0; h0 < NQ; h0 += BATCH) {
        dim3 cgrid(GX, K_OFFSETS, BATCH);
        conv2_kernel<<<cgrid, 256, 0, stream>>>(
            xin, wt, counts_hk, base_hk, pairlist, msg2, h0);
        gather2_kernel<<<(QPTS / 4) * BATCH, 256, 0, stream>>>(
            msg2, counts, idxbuf, bias, features, out, x1b, h0, layer);
      }
    }
  } else {
    dim3 cgrid((N_PAIRS + 63) / 64, K_OFFSETS);
    conv_atomic_kernel<<<cgrid, 256, 0, stream>>>(xb, WT0, in_map, out_map, out);
    mid_kernel<<<(N_POINTS * C / 4 + 255) / 256, 256, 0, stream>>>(features, b1, out, x1b);
    conv_atomic_kernel<<<cgrid, 256, 0, stream>>>(x1b, WT1, in_map, out_map, out);
  }
}

// Round 12
// 660.551 us; speedup vs baseline: 1.0232x; 1.0232x over previous
//
#include <hip/hip_runtime.h>

#define N_POINTS 100000
#define N_PAIRS  50000
#define K_OFFSETS 27
#define C 128
#define WPAD 136   // 128 + 8 bf16 pad; LDS row stride 272B
#define CAP 48     // per-point list capacity; Poisson(13.5), P(>=48) ~ 3e-12

// Point-quarter CSR (round-9 verified): per (h,k) bucket k-pure & contiguous ->
// conv writes msg linearly; gather reads each point once per layer.
#define NQ 4
#define QPTS 25000
#define MSGCAP 344064      // slots per quarter; mean 337.9K incl pads, +11 sigma
#define GX 110             // conv blocks per k: 110*128 = 14080 >= cnt_hk (+14 sigma)

// XCD-partitioned build (round-2 proven)
#define CSR_GROUPS 8
#define CSR_BPG 128

typedef __attribute__((ext_vector_type(8))) short short8;
typedef __attribute__((ext_vector_type(4))) float floatx4;
typedef __attribute__((ext_vector_type(4))) int intx4;            // nt-load-capable
typedef __attribute__((ext_vector_type(4))) unsigned int uintx4;  // nt-store-capable

__device__ inline unsigned short f2bf(float f) {
  unsigned int u = __float_as_uint(f);
  return (unsigned short)((u + 0x7FFFu + ((u >> 16) & 1u)) >> 16);  // RNE
}
__device__ inline float bf2f(unsigned int lo16) {
  return __uint_as_float(lo16 << 16);
}

// WT[k][d*C + c] = bf16(W[k][c][d])  -- natural order for BOTH layers
__global__ __launch_bounds__(256) void prep_w_kernel(
    const float* __restrict__ W0, const float* __restrict__ W1,
    unsigned short* __restrict__ WT0, unsigned short* __restrict__ WT1) {
  int i = blockIdx.x * 256 + threadIdx.x;
  const int per = K_OFFSETS * C * C;
  if (i >= 2 * per) return;
  const float* W = (i < per) ? W0 : W1;
  unsigned short* WT = (i < per) ? WT0 : WT1;
  int r = (i < per) ? i : i - per;
  int k = r / (C * C);
  int q = r % (C * C);
  int d = q / C;
  int c = q % C;
  WT[k * C * C + d * C + c] = f2bf(W[k * C * C + c * C + d]);
}

// xb = bf16(features); out = broadcast(b0) only on the fallback path
__global__ __launch_bounds__(256) void prep_x_kernel(
    const float* __restrict__ features, const float* __restrict__ b0,
    unsigned short* __restrict__ xb, float* __restrict__ out, int write_out) {
  int i = (blockIdx.x * 256 + threadIdx.x) * 4;
  if (i >= N_POINTS * C) return;
  float4 f = *(const float4*)&features[i];
  ushort4 u;
  u.x = f2bf(f.x); u.y = f2bf(f.y); u.z = f2bf(f.z); u.w = f2bf(f.w);
  *(ushort4*)&xb[i] = u;
  if (write_out) {
    float4 b = *(const float4*)&b0[i & 127];
    *(float4*)&out[i] = b;
  }
}

__global__ __launch_bounds__(256) void zero_meta_kernel(
    int* __restrict__ counts, int* __restrict__ counts_hk) {
  int i = blockIdx.x * 256 + threadIdx.x;
  if (i < N_POINTS) counts[i] = 0;
  if (i < NQ * K_OFFSETS) counts_hk[i] = 0;
}

// Pass 1: per-(quarter,k) totals. LDS histogram; nt loads keep the stream out of L2.
__global__ __launch_bounds__(256) void count_hk_kernel(
    const int* __restrict__ out_map, int* __restrict__ counts_hk) {
  __shared__ int hist[NQ * K_OFFSETS];
  if (threadIdx.x < NQ * K_OFFSETS) hist[threadIdx.x] = 0;
  __syncthreads();
  const int total4 = K_OFFSETS * N_PAIRS / 4;
  for (int i4 = blockIdx.x * 256 + (int)threadIdx.x; i4 < total4; i4 += 256 * 256) {
    intx4 o4 = __builtin_nontemporal_load((const intx4*)&out_map[i4 * 4]);
    int o[4] = {o4.x, o4.y, o4.z, o4.w};
    int k = (i4 * 4) / N_PAIRS;
#pragma unroll
    for (int j = 0; j < 4; ++j) atomicAdd(&hist[(o[j] / QPTS) * K_OFFSETS + k], 1);
  }
  __syncthreads();
  if (threadIdx.x < NQ * K_OFFSETS)
    atomicAdd(&counts_hk[threadIdx.x], hist[threadIdx.x]);
}

// Pass 2: exclusive scan of 32-padded bucket sizes, per quarter.
__global__ void scan_kernel(const int* __restrict__ counts_hk,
                            int* __restrict__ base_hk, int* __restrict__ cursor_hk) {
  if (threadIdx.x < NQ) {
    int h = threadIdx.x;
    int run = 0;
    for (int k = 0; k < K_OFFSETS; ++k) {
      base_hk[h * K_OFFSETS + k] = run;
      cursor_hk[h * K_OFFSETS + k] = run;
      run += (counts_hk[h * K_OFFSETS + k] + 31) & ~31;
    }
  }
}

// Pass 3: slot assignment + per-point lists. Two-level alloc (LDS hist -> one
// cursor atomicAdd per (block,k)).
__global__ __launch_bounds__(256) void build2_kernel(
    const int* __restrict__ out_map, const int* __restrict__ in_map,
    int* __restrict__ counts, int* __restrict__ idxbuf,
    int* __restrict__ cursor_hk, int* __restrict__ pairlist) {
  __shared__ int histA[K_OFFSETS];
  __shared__ int kbase[K_OFFSETS];
  const int grp = blockIdx.x & (CSR_GROUPS - 1);
  const int blk = blockIdx.x >> 3;
  const int h = grp >> 1;
  const int lo = grp * (N_POINTS / CSR_GROUPS);
  const int hi = lo + (N_POINTS / CSR_GROUPS);
  if (threadIdx.x < K_OFFSETS) histA[threadIdx.x] = 0;
  __syncthreads();
  const int total4 = K_OFFSETS * N_PAIRS / 4;
  for (int i4 = blk * 256 + (int)threadIdx.x; i4 < total4; i4 += CSR_BPG * 256) {
    intx4 o4 = __builtin_nontemporal_load((const intx4*)&out_map[i4 * 4]);
    int o[4] = {o4.x, o4.y, o4.z, o4.w};
    int k = (i4 * 4) / N_PAIRS;
#pragma unroll
    for (int j = 0; j < 4; ++j)
      if (o[j] >= lo && o[j] < hi) atomicAdd(&histA[k], 1);
  }
  __syncthreads();
  if (threadIdx.x < K_OFFSETS) {
    kbase[threadIdx.x] =
        atomicAdd(&cursor_hk[h * K_OFFSETS + threadIdx.x], histA[threadIdx.x]);
    histA[threadIdx.x] = 0;
  }
  __syncthreads();
  for (int i4 = blk * 256 + (int)threadIdx.x; i4 < total4; i4 += CSR_BPG * 256) {
    intx4 o4 = __builtin_nontemporal_load((const intx4*)&out_map[i4 * 4]);
    intx4 n4 = __builtin_nontemporal_load((const intx4*)&in_map[i4 * 4]);
    int o[4] = {o4.x, o4.y, o4.z, o4.w};
    int n[4] = {n4.x, n4.y, n4.z, n4.w};
    int k = (i4 * 4) / N_PAIRS;
#pragma unroll
    for (int j = 0; j < 4; ++j) {
      if (o[j] >= lo && o[j] < hi) {
        int pk = atomicAdd(&histA[k], 1);
        int slot = kbase[k] + pk;
        pairlist[h * MSGCAP + slot] = n[j];
        int pos = atomicAdd(&counts[o[j]], 1);
        if (pos < CAP) idxbuf[o[j] * CAP + pos] = slot;
      }
    }
  }
}

// Conv (quarters h0..h0+gridDim.z-1): wave = 32 contiguous slots = 2 A-tiles.
// pairlist coalesced, msg writes LINEAR + NON-TEMPORAL (msg2 is written once,
// read once -> nt store kills the write-allocate round-trip that round-11
// counters exposed: WRITE 232 vs 176 logical, FETCH +55 MB of allocate fills).
__global__ __launch_bounds__(256, 4) void conv2_kernel(
    const unsigned short* __restrict__ xin, const unsigned short* __restrict__ wbt,
    const int* __restrict__ counts_hk, const int* __restrict__ base_hk,
    const int* __restrict__ pairlist, unsigned short* __restrict__ msg2, int h0) {
  __shared__ unsigned short Wlds[C * WPAD];
  const int h = h0 + blockIdx.z;
  const int k = blockIdx.y;
  const int cnt = counts_hk[h * K_OFFSETS + k];
  const int cpad = (cnt + 31) & ~31;
  const int off0 = blockIdx.x * 128;
  if (off0 >= cpad) return;            // block-uniform, before any barrier
  const int kb = base_hk[h * K_OFFSETS + k];
  const int tid = threadIdx.x;

  const unsigned short* wk = wbt + k * C * C;
#pragma unroll
  for (int it = 0; it < 8; ++it) {
    int t = tid + it * 256;
    int row = t >> 4;
    int col = (t & 15) << 3;
    *(uint4*)&Wlds[row * WPAD + col] = *(const uint4*)&wk[row * C + col];
  }
  __syncthreads();

  const int wave = tid >> 6;
  const int lane = tid & 63;
  const int l15 = lane & 15;
  const int kg = lane >> 4;
  const int ws0 = off0 + wave * 32;
  if (ws0 >= cpad) return;             // wave-uniform (32-aligned windows)

  const int s0 = kb + ws0;
  const int plbase = h * MSGCAP;
  const int n0 = pairlist[plbase + s0 + l15] & 0x1FFFF;
  const int n1 = pairlist[plbase + s0 + 16 + l15] & 0x1FFFF;
  const unsigned short* arow0 = xin + (size_t)n0 * C + kg * 8;
  const unsigned short* arow1 = xin + (size_t)n1 * C + kg * 8;

  floatx4 acc0[8], acc1[8];
#pragma unroll
  for (int nt = 0; nt < 8; ++nt) {
    acc0[nt] = (floatx4){0.f, 0.f, 0.f, 0.f};
    acc1[nt] = (floatx4){0.f, 0.f, 0.f, 0.f};
  }
#pragma unroll
  for (int kk = 0; kk < 4; ++kk) {
    short8 a0 = *(const short8*)(arow0 + kk * 32);
    short8 a1 = *(const short8*)(arow1 + kk * 32);
    const unsigned short* bbase = &Wlds[l15 * WPAD + kk * 32 + kg * 8];
#pragma unroll
    for (int nt = 0; nt < 8; ++nt) {
      short8 b = *(const short8*)(bbase + nt * 16 * WPAD);
      acc0[nt] = __builtin_amdgcn_mfma_f32_16x16x32_bf16(a0, b, acc0[nt], 0, 0, 0);
      acc1[nt] = __builtin_amdgcn_mfma_f32_16x16x32_bf16(a1, b, acc1[nt], 0, 0, 0);
    }
  }
  unsigned short* mz = msg2 + (size_t)blockIdx.z * MSGCAP * C;
#pragma unroll
  for (int i = 0; i < 4; ++i) {
    {
      unsigned short* row = mz + (size_t)(s0 + kg * 4 + i) * C;
      uintx4 v;
      v.x = (unsigned int)f2bf(acc0[0][i]) | ((unsigned int)f2bf(acc0[1][i]) << 16);
      v.y = (unsigned int)f2bf(acc0[2][i]) | ((unsigned int)f2bf(acc0[3][i]) << 16);
      v.z = (unsigned int)f2bf(acc0[4][i]) | ((unsigned int)f2bf(acc0[5][i]) << 16);
      v.w = (unsigned int)f2bf(acc0[6][i]) | ((unsigned int)f2bf(acc0[7][i]) << 16);
      __builtin_nontemporal_store(v, (uintx4*)(row + l15 * 8));
    }
    {
      unsigned short* row = mz + (size_t)(s0 + 16 + kg * 4 + i) * C;
      uintx4 v;
      v.x = (unsigned int)f2bf(acc1[0][i]) | ((unsigned int)f2bf(acc1[1][i]) << 16);
      v.y = (unsigned int)f2bf(acc1[2][i]) | ((unsigned int)f2bf(acc1[3][i]) << 16);
      v.z = (unsigned int)f2bf(acc1[4][i]) | ((unsigned int)f2bf(acc1[5][i]) << 16);
      v.w = (unsigned int)f2bf(acc1[6][i]) | ((unsigned int)f2bf(acc1[7][i]) << 16);
      __builtin_nontemporal_store(v, (uintx4*)(row + l15 * 8));
    }
  }
}

// Gather (batched quarters): one wave per point, one pass over all 27 k.
__global__ __launch_bounds__(256) void gather2_kernel(
    const unsigned short* __restrict__ msg2, const int* __restrict__ counts,
    const int* __restrict__ idxbuf, const float* __restrict__ bias,
    const float* __restrict__ features, float* __restrict__ out,
    unsigned short* __restrict__ x1b, int h0, int layer) {
  __shared__ int elds[4][64];
  const int wave = threadIdx.x >> 6;
  const int lane = threadIdx.x & 63;
  const int z = blockIdx.x / (QPTS / 4);
  const int bx = blockIdx.x - z * (QPTS / 4);
  const int oi = (h0 + z) * QPTS + bx * 4 + wave;

  const int c0 = ((2 * lane) & 7) * 16 + (lane >> 2);
  const int c1 = c0 + 16;
  const size_t base = (size_t)oi * C;

  float a0, a1;
  if (layer == 0) { a0 = bias[c0]; a1 = bias[c1]; }
  else            { a0 = bias[c0] + features[base + c0];
                    a1 = bias[c1] + features[base + c1]; }

  int cnt = counts[oi]; if (cnt > CAP) cnt = CAP;
  if (lane < cnt) elds[wave][lane] = idxbuf[oi * CAP + lane];
  __syncthreads();

  const unsigned short* mb = msg2 + (size_t)z * MSGCAP * C + 2 * lane;
  int t = 0;
  for (; t + 4 <= cnt; t += 4) {
    int f0 = elds[wave][t];
    int f1 = elds[wave][t + 1];
    int f2 = elds[wave][t + 2];
    int f3 = elds[wave][t + 3];
    unsigned int v0 = *(const unsigned int*)(mb + (size_t)f0 * C);
    unsigned int v1 = *(const unsigned int*)(mb + (size_t)f1 * C);
    unsigned int v2 = *(const unsigned int*)(mb + (size_t)f2 * C);
    unsigned int v3 = *(const unsigned int*)(mb + (size_t)f3 * C);
    a0 += bf2f(v0 & 0xffffu) + bf2f(v1 & 0xffffu) + bf2f(v2 & 0xffffu) + bf2f(v3 & 0xffffu);
    a1 += bf2f(v0 >> 16) + bf2f(v1 >> 16) + bf2f(v2 >> 16) + bf2f(v3 >> 16);
  }
  for (; t < cnt; ++t) {
    int f0 = elds[wave][t];
    unsigned int v = *(const unsigned int*)(mb + (size_t)f0 * C);
    a0 += bf2f(v & 0xffffu);
    a1 += bf2f(v >> 16);
  }

  if (layer == 0) {
    x1b[base + c0] = f2bf(fmaxf(a0, 0.f));
    x1b[base + c1] = f2bf(fmaxf(a1, 0.f));
  } else {
    out[base + c0] = a0;
    out[base + c1] = a1;
  }
}

// ---------------- fallback (atomic path, small ws, natural WT) ----------------
__global__ __launch_bounds__(256) void mid_kernel(
    const float* __restrict__ features, const float* __restrict__ b1,
    float* __restrict__ out, unsigned short* __restrict__ x1b) {
  int i = (blockIdx.x * 256 + threadIdx.x) * 4;
  if (i >= N_POINTS * C) return;
  float4 y = *(const float4*)&out[i];
  ushort4 u;
  u.x = f2bf(fmaxf(y.x, 0.f));
  u.y = f2bf(fmaxf(y.y, 0.f));
  u.z = f2bf(fmaxf(y.z, 0.f));
  u.w = f2bf(fmaxf(y.w, 0.f));
  *(ushort4*)&x1b[i] = u;
  float4 f = *(const float4*)&features[i];
  float4 b = *(const float4*)&b1[i & 127];
  float4 o;
  o.x = f.x + b.x; o.y = f.y + b.y; o.z = f.z + b.z; o.w = f.w + b.w;
  *(float4*)&out[i] = o;
}

__global__ __launch_bounds__(256, 4) void conv_atomic_kernel(
    const unsigned short* __restrict__ xb, const unsigned short* __restrict__ wbt,
    const int* __restrict__ in_map, const int* __restrict__ out_map,
    float* __restrict__ out) {
  __shared__ unsigned short Wlds[C * WPAD];
  const int k = blockIdx.y;
  const int pairBase = blockIdx.x * 64;
  const int tid = threadIdx.x;
  const unsigned short* wk = wbt + k * C * C;
#pragma unroll
  for (int it = 0; it < 8; ++it) {
    int t = tid + it * 256;
    int row = t >> 4;
    int col = (t & 15) << 3;
    *(uint4*)&Wlds[row * WPAD + col] = *(const uint4*)&wk[row * C + col];
  }
  __syncthreads();
  const int wave = tid >> 6;
  const int lane = tid & 63;
  const int l15 = lane & 15;
  const int kg = lane >> 4;
  const int pair0 = pairBase + wave * 16;
  const int prA = pair0 + l15;
  const int inIdx = (prA < N_PAIRS) ? in_map[k * N_PAIRS + prA] : 0;
  const unsigned short* arow = xb + (size_t)inIdx * C + kg * 8;
  floatx4 acc[8];
#pragma unroll
  for (int nt = 0; nt < 8; ++nt) acc[nt] = (floatx4){0.f, 0.f, 0.f, 0.f};
#pragma unroll
  for (int kk = 0; kk < 4; ++kk) {
    short8 a = *(const short8*)(arow + kk * 32);
    const unsigned short* bbase = &Wlds[l15 * WPAD + kk * 32 + kg * 8];
#pragma unroll
    for (int nt = 0; nt < 8; ++nt) {
      short8 b = *(const short8*)(bbase + nt * 16 * WPAD);
      acc[nt] = __builtin_amdgcn_mfma_f32_16x16x32_bf16(a, b, acc[nt], 0, 0, 0);
    }
  }
#pragma unroll
  for (int i = 0; i < 4; ++i) {
    int pr = pair0 + kg * 4 + i;
    if (pr < N_PAIRS) {
      int oi = out_map[k * N_PAIRS + pr];
      float* orow = out + (size_t)oi * C + l15;
#pragma unroll
      for (int nt = 0; nt < 8; ++nt) atomicAdd(orow + nt * 16, acc[nt][i]);
    }
  }
}

extern "C" void kernel_launch(void* const* d_in, const int* in_sizes, int n_in,
                              void* d_out, int out_size, void* d_ws, size_t ws_size,
                              hipStream_t stream) {
  const float* features = (const float*)d_in[0];
  const int* in_map     = (const int*)d_in[1];
  const int* out_map    = (const int*)d_in[2];
  const float* W0       = (const float*)d_in[3];
  const float* b0       = (const float*)d_in[4];
  const float* W1       = (const float*)d_in[5];
  const float* b1       = (const float*)d_in[6];
  float* out = (float*)d_out;

  char* ws = (char*)d_ws;
  unsigned short* xb  = (unsigned short*)(ws);                  // 25,600,000
  unsigned short* x1b = (unsigned short*)(ws + 25600000);       // 25,600,000
  unsigned short* WT0 = (unsigned short*)(ws + 51200000);       //    884,736
  unsigned short* WT1 = (unsigned short*)(ws + 52084736);       //    884,736
  int* counts         = (int*)(ws + 52969472);                  //    400,384
  int* counts_hk      = (int*)(ws + 53369856);                  //        512
  int* base_hk        = (int*)(ws + 53370368);                  //        512
  int* cursor_hk      = (int*)(ws + 53370880);                  //        512
  int* pairlist       = (int*)(ws + 53371392);                  //  5,505,024 (4 x MSGCAP x 4)
  int* idxbuf         = (int*)(ws + 58876416);                  // 19,200,000 (100000*CAP*4)
  unsigned short* msg2 = (unsigned short*)(ws + 78076416);      // B x 88,080,384 (MSGCAP*256)
  // 1-batch end = 166,156,800 ; 2-batch end = 254,237,184

  const int use2  = (ws_size >= 166156800ULL) ? 1 : 0;
  const int BATCH = (ws_size >= 254237184ULL) ? 2 : 1;

  prep_w_kernel<<<(2 * K_OFFSETS * C * C + 255) / 256, 256, 0, stream>>>(W0, W1, WT0, WT1);
  prep_x_kernel<<<(N_POINTS * C / 4 + 255) / 256, 256, 0, stream>>>(
      features, b0, xb, out, use2 ? 0 : 1);

  if (use2) {
    zero_meta_kernel<<<(N_POINTS + 255) / 256, 256, 0, stream>>>(counts, counts_hk);
    count_hk_kernel<<<256, 256, 0, stream>>>(out_map, counts_hk);
    scan_kernel<<<1, 64, 0, stream>>>(counts_hk, base_hk, cursor_hk);
    build2_kernel<<<CSR_GROUPS * CSR_BPG, 256, 0, stream>>>(
        out_map, in_map, counts, idxbuf, cursor_hk, pairlist);

    for (int layer = 0; layer < 2; ++layer) {
      const unsigned short* xin = layer ? x1b : xb;
      const unsigned short* wt  = layer ? WT1 : WT0;
      const float* bias         = layer ? b1  : b0;
      for (int h0 = 0; h0 < NQ; h0 += BATCH) {
        dim3 cgrid(GX, K_OFFSETS, BATCH);
        conv2_kernel<<<cgrid, 256, 0, stream>>>(
            xin, wt, counts_hk, base_hk, pairlist, msg2, h0);
        gather2_kernel<<<(QPTS / 4) * BATCH, 256, 0, stream>>>(
            msg2, counts, idxbuf, bias, features, out, x1b, h0, layer);
      }
    }
  } else {
    dim3 cgrid((N_PAIRS + 63) / 64, K_OFFSETS);
    conv_atomic_kernel<<<cgrid, 256, 0, stream>>>(xb, WT0, in_map, out_map, out);
    mid_kernel<<<(N_POINTS * C / 4 + 255) / 256, 256, 0, stream>>>(features, b1, out, x1b);
    conv_atomic_kernel<<<cgrid, 256, 0, stream>>>(x1b, WT1, in_map, out_map, out);
  }
}

// Round 14
// 645.299 us; speedup vs baseline: 1.0474x; 1.0236x over previous
//
#include <hip/hip_runtime.h>

#define N_POINTS 100000
#define N_PAIRS  50000
#define K_OFFSETS 27
#define C 128
#define WPAD 136   // 128 + 8 bf16 pad; LDS row stride 272B
#define CAP 48     // per-point list capacity; Poisson(13.5), P(>=48) ~ 3e-12

// Point-quarter CSR (round-9/12 verified): per (h,k) bucket k-pure & contiguous.
// Round-13: buckets are internally split into two GROUP-PURE sub-ranges so the
// two XCD-groups of a quarter never write the same pairlist line (cross-XCD
// line ping-pong was the residual build2 write amplification).
#define NQ 4
#define QPTS 25000
#define MSGCAP 344064      // slots per quarter; mean 337.9K incl pads, +11 sigma
#define GX 110             // conv blocks per k: 110*128 = 14080 >= cnt_hk (+14 sigma)

// XCD-partitioned build (round-2 proven)
#define CSR_GROUPS 8
#define CSR_BPG 128

typedef __attribute__((ext_vector_type(8))) short short8;
typedef __attribute__((ext_vector_type(4))) float floatx4;
typedef __attribute__((ext_vector_type(4))) int intx4;            // nt-load-capable
typedef __attribute__((ext_vector_type(4))) unsigned int uintx4;  // nt-store-capable

__device__ inline unsigned short f2bf(float f) {
  unsigned int u = __float_as_uint(f);
  return (unsigned short)((u + 0x7FFFu + ((u >> 16) & 1u)) >> 16);  // RNE
}
__device__ inline float bf2f(unsigned int lo16) {
  return __uint_as_float(lo16 << 16);
}

// WT[k][d*C + c] = bf16(W[k][c][d])  -- natural order for BOTH layers
__global__ __launch_bounds__(256) void prep_w_kernel(
    const float* __restrict__ W0, const float* __restrict__ W1,
    unsigned short* __restrict__ WT0, unsigned short* __restrict__ WT1) {
  int i = blockIdx.x * 256 + threadIdx.x;
  const int per = K_OFFSETS * C * C;
  if (i >= 2 * per) return;
  const float* W = (i < per) ? W0 : W1;
  unsigned short* WT = (i < per) ? WT0 : WT1;
  int r = (i < per) ? i : i - per;
  int k = r / (C * C);
  int q = r % (C * C);
  int d = q / C;
  int c = q % C;
  WT[k * C * C + d * C + c] = f2bf(W[k * C * C + c * C + d]);
}

// xb = bf16(features); out = broadcast(b0) only on the fallback path
__global__ __launch_bounds__(256) void prep_x_kernel(
    const float* __restrict__ features, const float* __restrict__ b0,
    unsigned short* __restrict__ xb, float* __restrict__ out, int write_out) {
  int i = (blockIdx.x * 256 + threadIdx.x) * 4;
  if (i >= N_POINTS * C) return;
  float4 f = *(const float4*)&features[i];
  ushort4 u;
  u.x = f2bf(f.x); u.y = f2bf(f.y); u.z = f2bf(f.z); u.w = f2bf(f.w);
  *(ushort4*)&xb[i] = u;
  if (write_out) {
    float4 b = *(const float4*)&b0[i & 127];
    *(float4*)&out[i] = b;
  }
}

__global__ __launch_bounds__(256) void zero_meta_kernel(
    int* __restrict__ counts, int* __restrict__ counts_gk) {
  int i = blockIdx.x * 256 + threadIdx.x;
  if (i < N_POINTS) counts[i] = 0;
  if (i < CSR_GROUPS * K_OFFSETS) counts_gk[i] = 0;
}

// Pass 1: per-(group,k) totals (216 bins). LDS histogram; nt loads.
__global__ __launch_bounds__(256) void count_gk_kernel(
    const int* __restrict__ out_map, int* __restrict__ counts_gk) {
  __shared__ int hist[CSR_GROUPS * K_OFFSETS];
  if (threadIdx.x < CSR_GROUPS * K_OFFSETS) hist[threadIdx.x] = 0;
  __syncthreads();
  const int total4 = K_OFFSETS * N_PAIRS / 4;
  for (int i4 = blockIdx.x * 256 + (int)threadIdx.x; i4 < total4; i4 += 256 * 256) {
    intx4 o4 = __builtin_nontemporal_load((const intx4*)&out_map[i4 * 4]);
    int o[4] = {o4.x, o4.y, o4.z, o4.w};
    int k = (i4 * 4) / N_PAIRS;
#pragma unroll
    for (int j = 0; j < 4; ++j)
      atomicAdd(&hist[(o[j] / (N_POINTS / CSR_GROUPS)) * K_OFFSETS + k], 1);
  }
  __syncthreads();
  if (threadIdx.x < CSR_GROUPS * K_OFFSETS)
    atomicAdd(&counts_gk[threadIdx.x], hist[threadIdx.x]);
}

// Pass 2: per-quarter bucket layout. Bucket (h,k) = [grp 2h sub-range][grp 2h+1
// sub-range][pad to 32]. cursor_gk gives each group its own disjoint slot range
// -> pairlist lines are single-XCD.
__global__ void scan_kernel(const int* __restrict__ counts_gk,
                            int* __restrict__ counts_hk, int* __restrict__ base_hk,
                            int* __restrict__ cursor_gk) {
  if (threadIdx.x < NQ) {
    int h = threadIdx.x;
    int run = 0;
    for (int k = 0; k < K_OFFSETS; ++k) {
      int c0 = counts_gk[(2 * h) * K_OFFSETS + k];
      int c1 = counts_gk[(2 * h + 1) * K_OFFSETS + k];
      base_hk[h * K_OFFSETS + k] = run;
      counts_hk[h * K_OFFSETS + k] = c0 + c1;
      cursor_gk[(2 * h) * K_OFFSETS + k] = run;
      cursor_gk[(2 * h + 1) * K_OFFSETS + k] = run + c0;
      run += (c0 + c1 + 31) & ~31;
    }
  }
}

// Pass 3: slot assignment + per-point lists. Two-level alloc (LDS hist -> one
// cursor atomicAdd per (block, grp, k)); all global accumulators group-pure.
__global__ __launch_bounds__(256) void build2_kernel(
    const int* __restrict__ out_map, const int* __restrict__ in_map,
    int* __restrict__ counts, int* __restrict__ idxbuf,
    int* __restrict__ cursor_gk, int* __restrict__ pairlist) {
  __shared__ int histA[K_OFFSETS];
  __shared__ int kbase[K_OFFSETS];
  const int grp = blockIdx.x & (CSR_GROUPS - 1);
  const int blk = blockIdx.x >> 3;
  const int h = grp >> 1;
  const int lo = grp * (N_POINTS / CSR_GROUPS);
  const int hi = lo + (N_POINTS / CSR_GROUPS);
  if (threadIdx.x < K_OFFSETS) histA[threadIdx.x] = 0;
  __syncthreads();
  const int total4 = K_OFFSETS * N_PAIRS / 4;
  for (int i4 = blk * 256 + (int)threadIdx.x; i4 < total4; i4 += CSR_BPG * 256) {
    intx4 o4 = __builtin_nontemporal_load((const intx4*)&out_map[i4 * 4]);
    int o[4] = {o4.x, o4.y, o4.z, o4.w};
    int k = (i4 * 4) / N_PAIRS;
#pragma unroll
    for (int j = 0; j < 4; ++j)
      if (o[j] >= lo && o[j] < hi) atomicAdd(&histA[k], 1);
  }
  __syncthreads();
  if (threadIdx.x < K_OFFSETS) {
    kbase[threadIdx.x] =
        atomicAdd(&cursor_gk[grp * K_OFFSETS + threadIdx.x], histA[threadIdx.x]);
    histA[threadIdx.x] = 0;
  }
  __syncthreads();
  for (int i4 = blk * 256 + (int)threadIdx.x; i4 < total4; i4 += CSR_BPG * 256) {
    intx4 o4 = __builtin_nontemporal_load((const intx4*)&out_map[i4 * 4]);
    intx4 n4 = __builtin_nontemporal_load((const intx4*)&in_map[i4 * 4]);
    int o[4] = {o4.x, o4.y, o4.z, o4.w};
    int n[4] = {n4.x, n4.y, n4.z, n4.w};
    int k = (i4 * 4) / N_PAIRS;
#pragma unroll
    for (int j = 0; j < 4; ++j) {
      if (o[j] >= lo && o[j] < hi) {
        int pk = atomicAdd(&histA[k], 1);
        int slot = kbase[k] + pk;
        pairlist[h * MSGCAP + slot] = n[j];
        int pos = atomicAdd(&counts[o[j]], 1);
        if (pos < CAP) idxbuf[o[j] * CAP + pos] = slot;
      }
    }
  }
}

// Conv (quarters h0..h0+gridDim.z-1): wave = 32 contiguous slots = 2 A-tiles.
// pairlist coalesced, msg writes LINEAR + NON-TEMPORAL (write-once read-once).
__global__ __launch_bounds__(256, 4) void conv2_kernel(
    const unsigned short* __restrict__ xin, const unsigned short* __restrict__ wbt,
    const int* __restrict__ counts_hk, const int* __restrict__ base_hk,
    const int* __restrict__ pairlist, unsigned short* __restrict__ msg2, int h0) {
  __shared__ unsigned short Wlds[C * WPAD];
  const int h = h0 + blockIdx.z;
  const int k = blockIdx.y;
  const int cnt = counts_hk[h * K_OFFSETS + k];
  const int cpad = (cnt + 31) & ~31;
  const int off0 = blockIdx.x * 128;
  if (off0 >= cpad) return;            // block-uniform, before any barrier
  const int kb = base_hk[h * K_OFFSETS + k];
  const int tid = threadIdx.x;

  const unsigned short* wk = wbt + k * C * C;
#pragma unroll
  for (int it = 0; it < 8; ++it) {
    int t = tid + it * 256;
    int row = t >> 4;
    int col = (t & 15) << 3;
    *(uint4*)&Wlds[row * WPAD + col] = *(const uint4*)&wk[row * C + col];
  }
  __syncthreads();

  const int wave = tid >> 6;
  const int lane = tid & 63;
  const int l15 = lane & 15;
  const int kg = lane >> 4;
  const int ws0 = off0 + wave * 32;
  if (ws0 >= cpad) return;             // wave-uniform (32-aligned windows)

  const int s0 = kb + ws0;
  const int plbase = h * MSGCAP;
  const int n0 = pairlist[plbase + s0 + l15] & 0x1FFFF;
  const int n1 = pairlist[plbase + s0 + 16 + l15] & 0x1FFFF;
  const unsigned short* arow0 = xin + (size_t)n0 * C + kg * 8;
  const unsigned short* arow1 = xin + (size_t)n1 * C + kg * 8;

  floatx4 acc0[8], acc1[8];
#pragma unroll
  for (int nt = 0; nt < 8; ++nt) {
    acc0[nt] = (floatx4){0.f, 0.f, 0.f, 0.f};
    acc1[nt] = (floatx4){0.f, 0.f, 0.f, 0.f};
  }
#pragma unroll
  for (int kk = 0; kk < 4; ++kk) {
    short8 a0 = *(const short8*)(arow0 + kk * 32);
    short8 a1 = *(const short8*)(arow1 + kk * 32);
    const unsigned short* bbase = &Wlds[l15 * WPAD + kk * 32 + kg * 8];
#pragma unroll
    for (int nt = 0; nt < 8; ++nt) {
      short8 b = *(const short8*)(bbase + nt * 16 * WPAD);
      acc0[nt] = __builtin_amdgcn_mfma_f32_16x16x32_bf16(a0, b, acc0[nt], 0, 0, 0);
      acc1[nt] = __builtin_amdgcn_mfma_f32_16x16x32_bf16(a1, b, acc1[nt], 0, 0, 0);
    }
  }
  unsigned short* mz = msg2 + (size_t)blockIdx.z * MSGCAP * C;
#pragma unroll
  for (int i = 0; i < 4; ++i) {
    {
      unsigned short* row = mz + (size_t)(s0 + kg * 4 + i) * C;
      uintx4 v;
      v.x = (unsigned int)f2bf(acc0[0][i]) | ((unsigned int)f2bf(acc0[1][i]) << 16);
      v.y = (unsigned int)f2bf(acc0[2][i]) | ((unsigned int)f2bf(acc0[3][i]) << 16);
      v.z = (unsigned int)f2bf(acc0[4][i]) | ((unsigned int)f2bf(acc0[5][i]) << 16);
      v.w = (unsigned int)f2bf(acc0[6][i]) | ((unsigned int)f2bf(acc0[7][i]) << 16);
      __builtin_nontemporal_store(v, (uintx4*)(row + l15 * 8));
    }
    {
      unsigned short* row = mz + (size_t)(s0 + 16 + kg * 4 + i) * C;
      uintx4 v;
      v.x = (unsigned int)f2bf(acc1[0][i]) | ((unsigned int)f2bf(acc1[1][i]) << 16);
      v.y = (unsigned int)f2bf(acc1[2][i]) | ((unsigned int)f2bf(acc1[3][i]) << 16);
      v.z = (unsigned int)f2bf(acc1[4][i]) | ((unsigned int)f2bf(acc1[5][i]) << 16);
      v.w = (unsigned int)f2bf(acc1[6][i]) | ((unsigned int)f2bf(acc1[7][i]) << 16);
      __builtin_nontemporal_store(v, (uintx4*)(row + l15 * 8));
    }
  }
}

// Gather (batched quarters): one wave per point, one pass over all 27 k.
// msg rows and idxbuf lists are read-once -> nt loads keep them from evicting
// xb/features/counts from L2/L3.
__global__ __launch_bounds__(256) void gather2_kernel(
    const unsigned short* __restrict__ msg2, const int* __restrict__ counts,
    const int* __restrict__ idxbuf, const float* __restrict__ bias,
    const float* __restrict__ features, float* __restrict__ out,
    unsigned short* __restrict__ x1b, int h0, int layer) {
  __shared__ int elds[4][64];
  const int wave = threadIdx.x >> 6;
  const int lane = threadIdx.x & 63;
  const int z = blockIdx.x / (QPTS / 4);
  const int bx = blockIdx.x - z * (QPTS / 4);
  const int oi = (h0 + z) * QPTS + bx * 4 + wave;

  const int c0 = ((2 * lane) & 7) * 16 + (lane >> 2);
  const int c1 = c0 + 16;
  const size_t base = (size_t)oi * C;

  float a0, a1;
  if (layer == 0) { a0 = bias[c0]; a1 = bias[c1]; }
  else            { a0 = bias[c0] + features[base + c0];
                    a1 = bias[c1] + features[base + c1]; }

  int cnt = counts[oi]; if (cnt > CAP) cnt = CAP;
  if (lane < cnt)
    elds[wave][lane] = __builtin_nontemporal_load(&idxbuf[oi * CAP + lane]);
  __syncthreads();

  const unsigned short* mb = msg2 + (size_t)z * MSGCAP * C + 2 * lane;
  int t = 0;
  for (; t + 4 <= cnt; t += 4) {
    int f0 = elds[wave][t];
    int f1 = elds[wave][t + 1];
    int f2 = elds[wave][t + 2];
    int f3 = elds[wave][t + 3];
    unsigned int v0 = __builtin_nontemporal_load((const unsigned int*)(mb + (size_t)f0 * C));
    unsigned int v1 = __builtin_nontemporal_load((const unsigned int*)(mb + (size_t)f1 * C));
    unsigned int v2 = __builtin_nontemporal_load((const unsigned int*)(mb + (size_t)f2 * C));
    unsigned int v3 = __builtin_nontemporal_load((const unsigned int*)(mb + (size_t)f3 * C));
    a0 += bf2f(v0 & 0xffffu) + bf2f(v1 & 0xffffu) + bf2f(v2 & 0xffffu) + bf2f(v3 & 0xffffu);
    a1 += bf2f(v0 >> 16) + bf2f(v1 >> 16) + bf2f(v2 >> 16) + bf2f(v3 >> 16);
  }
  for (; t < cnt; ++t) {
    int f0 = elds[wave][t];
    unsigned int v = __builtin_nontemporal_load((const unsigned int*)(mb + (size_t)f0 * C));
    a0 += bf2f(v & 0xffffu);
    a1 += bf2f(v >> 16);
  }

  if (layer == 0) {
    x1b[base + c0] = f2bf(fmaxf(a0, 0.f));
    x1b[base + c1] = f2bf(fmaxf(a1, 0.f));
  } else {
    out[base + c0] = a0;
    out[base + c1] = a1;
  }
}

// ---------------- fallback (atomic path, small ws, natural WT) ----------------
__global__ __launch_bounds__(256) void mid_kernel(
    const float* __restrict__ features, const float* __restrict__ b1,
    float* __restrict__ out, unsigned short* __restrict__ x1b) {
  int i = (blockIdx.x * 256 + threadIdx.x) * 4;
  if (i >= N_POINTS * C) return;
  float4 y = *(const float4*)&out[i];
  ushort4 u;
  u.x = f2bf(fmaxf(y.x, 0.f));
  u.y = f2bf(fmaxf(y.y, 0.f));
  u.z = f2bf(fmaxf(y.z, 0.f));
  u.w = f2bf(fmaxf(y.w, 0.f));
  *(ushort4*)&x1b[i] = u;
  float4 f = *(const float4*)&features[i];
  float4 b = *(const float4*)&b1[i & 127];
  float4 o;
  o.x = f.x + b.x; o.y = f.y + b.y; o.z = f.z + b.z; o.w = f.w + b.w;
  *(float4*)&out[i] = o;
}

__global__ __launch_bounds__(256, 4) void conv_atomic_kernel(
    const unsigned short* __restrict__ xb, const unsigned short* __restrict__ wbt,
    const int* __restrict__ in_map, const int* __restrict__ out_map,
    float* __restrict__ out) {
  __shared__ unsigned short Wlds[C * WPAD];
  const int k = blockIdx.y;
  const int pairBase = blockIdx.x * 64;
  const int tid = threadIdx.x;
  const unsigned short* wk = wbt + k * C * C;
#pragma unroll
  for (int it = 0; it < 8; ++it) {
    int t = tid + it * 256;
    int row = t >> 4;
    int col = (t & 15) << 3;
    *(uint4*)&Wlds[row * WPAD + col] = *(const uint4*)&wk[row * C + col];
  }
  __syncthreads();
  const int wave = tid >> 6;
  const int lane = tid & 63;
  const int l15 = lane & 15;
  const int kg = lane >> 4;
  const int pair0 = pairBase + wave * 16;
  const int prA = pair0 + l15;
  const int inIdx = (prA < N_PAIRS) ? in_map[k * N_PAIRS + prA] : 0;
  const unsigned short* arow = xb + (size_t)inIdx * C + kg * 8;
  floatx4 acc[8];
#pragma unroll
  for (int nt = 0; nt < 8; ++nt) acc[nt] = (floatx4){0.f, 0.f, 0.f, 0.f};
#pragma unroll
  for (int kk = 0; kk < 4; ++kk) {
    short8 a = *(const short8*)(arow + kk * 32);
    const unsigned short* bbase = &Wlds[l15 * WPAD + kk * 32 + kg * 8];
#pragma unroll
    for (int nt = 0; nt < 8; ++nt) {
      short8 b = *(const short8*)(bbase + nt * 16 * WPAD);
      acc[nt] = __builtin_amdgcn_mfma_f32_16x16x32_bf16(a, b, acc[nt], 0, 0, 0);
    }
  }
#pragma unroll
  for (int i = 0; i < 4; ++i) {
    int pr = pair0 + kg * 4 + i;
    if (pr < N_PAIRS) {
      int oi = out_map[k * N_PAIRS + pr];
      float* orow = out + (size_t)oi * C + l15;
#pragma unroll
      for (int nt = 0; nt < 8; ++nt) atomicAdd(orow + nt * 16, acc[nt][i]);
    }
  }
}

extern "C" void kernel_launch(void* const* d_in, const int* in_sizes, int n_in,
                              void* d_out, int out_size, void* d_ws, size_t ws_size,
                              hipStream_t stream) {
  const float* features = (const float*)d_in[0];
  const int* in_map     = (const int*)d_in[1];
  const int* out_map    = (const int*)d_in[2];
  const float* W0       = (const float*)d_in[3];
  const float* b0       = (const float*)d_in[4];
  const float* W1       = (const float*)d_in[5];
  const float* b1       = (const float*)d_in[6];
  float* out = (float*)d_out;

  char* ws = (char*)d_ws;
  unsigned short* xb  = (unsigned short*)(ws);                  // 25,600,000
  unsigned short* x1b = (unsigned short*)(ws + 25600000);       // 25,600,000
  unsigned short* WT0 = (unsigned short*)(ws + 51200000);       //    884,736
  unsigned short* WT1 = (unsigned short*)(ws + 52084736);       //    884,736
  int* counts         = (int*)(ws + 52969472);                  //    400,384
  int* counts_gk      = (int*)(ws + 53369856);                  //      1,024 (216 used)
  int* cursor_gk      = (int*)(ws + 53370880);                  //      1,024 (216 used)
  int* counts_hk      = (int*)(ws + 53371904);                  //        512 (108 used)
  int* base_hk        = (int*)(ws + 53372416);                  //        512 (108 used)
  int* pairlist       = (int*)(ws + 53372928);                  //  5,505,024 (4 x MSGCAP x 4)
  int* idxbuf         = (int*)(ws + 58877952);                  // 19,200,000 (100000*CAP*4)
  unsigned short* msg2 = (unsigned short*)(ws + 78077952);      // B x 88,080,384 (MSGCAP*256)
  // 1-batch end = 166,158,336 ; 2-batch end = 254,238,720

  const int use2  = (ws_size >= 166158336ULL) ? 1 : 0;
  const int BATCH = (ws_size >= 254238720ULL) ? 2 : 1;

  prep_w_kernel<<<(2 * K_OFFSETS * C * C + 255) / 256, 256, 0, stream>>>(W0, W1, WT0, WT1);
  prep_x_kernel<<<(N_POINTS * C / 4 + 255) / 256, 256, 0, stream>>>(
      features, b0, xb, out, use2 ? 0 : 1);

  if (use2) {
    zero_meta_kernel<<<(N_POINTS + 255) / 256, 256, 0, stream>>>(counts, counts_gk);
    count_gk_kernel<<<256, 256, 0, stream>>>(out_map, counts_gk);
    scan_kernel<<<1, 64, 0, stream>>>(counts_gk, counts_hk, base_hk, cursor_gk);
    build2_kernel<<<CSR_GROUPS * CSR_BPG, 256, 0, stream>>>(
        out_map, in_map, counts, idxbuf, cursor_gk, pairlist);

    for (int layer = 0; layer < 2; ++layer) {
      const unsigned short* xin = layer ? x1b : xb;
      const unsigned short* wt  = layer ? WT1 : WT0;
      const float* bias         = layer ? b1  : b0;
      for (int h0 = 0; h0 < NQ; h0 += BATCH) {
        dim3 cgrid(GX, K_OFFSETS, BATCH);
        conv2_kernel<<<cgrid, 256, 0, stream>>>(
            xin, wt, counts_hk, base_hk, pairlist, msg2, h0);
        gather2_kernel<<<(QPTS / 4) * BATCH, 256, 0, stream>>>(
            msg2, counts, idxbuf, bias, features, out, x1b, h0, layer);
      }
    }
  } else {
    dim3 cgrid((N_PAIRS + 63) / 64, K_OFFSETS);
    conv_atomic_kernel<<<cgrid, 256, 0, stream>>>(xb, WT0, in_map, out_map, out);
    mid_kernel<<<(N_POINTS * C / 4 + 255) / 256, 256, 0, stream>>>(features, b1, out, x1b);
    conv_atomic_kernel<<<cgrid, 256, 0, stream>>>(x1b, WT1, in_map, out_map, out);
  }
}